// Round 6
// baseline (215.522 us; speedup 1.0000x reference)
//
#include <hip/hip_runtime.h>
#include <hip/hip_bf16.h>

// GCN fused pipeline for MI355X — block-local counting sort (NO global atomics,
// NO scattered global writes), binary-search output-major merge, LDS-local
// E-passes, 8-way sharded pooling atomics.
// vocab=1 => h1[i] = relu(embW1*c_i + b1) piecewise-linear in scalar c_i with
// <=65 ReLU patterns (bins). g[i] = a_i*P[bin_i] + b_i*Q[bin_i].
// agg_i[d] = sum_u A_i[u]*P[u][d] + B_i[u]*Q[u][d], (A,B) per-(node,bin) LDS
// sums (2 LDS atomics/edge).
// Lessons: R6 - no E-scale global atomics (64B line write-through each);
// R11 - no cooperative grid.sync (8 XCDs); R12 - contended global atomic
// flush is a 71us-class floor -> shard psum/cnt; R13 - raising k_group blocks
// WITH global cursor atomics quadruples atomic write-through; R14 - 512-thr
// passC regressed (VGPR cap); R15 - output-major merge passA; R16 - per-edge
// wave-serialized broadcast loop = ~235 cyc/edge latency chain (615us!) —
// keep edges parallel ACROSS LANES; R17 - k_group GPB 128->256 neutral:
// k_group is NOT block-count-bound (internal latency/barrier structure).
// R18 (this round): passC U-loop has a DEPENDENT global PQ load per
// iteration (VALUBusy 15% @ 26.6% occ = stall signature). Software-pipeline
// it: prefetch PQ[u+1] while computing u; iterate u=0..63 directly (flags
// are global => U~65 always; ballot/ulist machinery deleted), bin-64 column
// via LDS. Front-end = R15 exact (GPB=128).
// Inputs: 0 x[int32 N], 1 edge_index[int32 2*E] (src then dst), 2 batch[int32 N sorted],
// 3 emb[1*64], 4 W1[64*64], 5 b1[64], 6 W2[64*64], 7 b2[64], 8 fcW[64*32], 9 fcb[32].
// Output: [G=64, 32] fp32.

#define DH 64
#define DOUT 32
#define NBIN 65
#define BW 64          // bucket width (nodes per bucket)
#define MAXNB 2048     // max buckets (N <= 131072)
#define SCAN_N 2048    // scan width (>= NB, pow2)
#define SRCM 0x3FFFFFF // 26-bit src mask (N < 2^26)
#define CAPE 1280      // per-bucket compacted capacity (16B-aligned: 1280*4=5120)
#define GPB 128        // group blocks; chunk = E/GPB ~ 12500 (fits u16 idx)
#define NSH 8          // pooling shards

// ---- group: per-block LDS counting sort -> block-private dense region + u16
// run index. Extra NBIN blocks compute PQ tables. ----
__global__ __launch_bounds__(1024) void k_group(
        const int* __restrict__ src, const int* __restrict__ dst,
        unsigned* __restrict__ rec, unsigned short* __restrict__ idx,
        const float* __restrict__ emb, const float* __restrict__ W1,
        const float* __restrict__ b1, const float* __restrict__ W2,
        float* __restrict__ tarr, float2* __restrict__ PQ, int E, int NB, int chunk) {
    __shared__ int lh[SCAN_N];
    __shared__ int lb[SCAN_N];
    __shared__ float ewl[DH], tl[DH], bl[DH];
    __shared__ int rl[DH], sl[DH];
    int tid = threadIdx.x, bid = blockIdx.x;
    if (bid >= GPB) {
        // ---- tables part: beta = bid-GPB in 0..64, 64 working threads ----
        int beta = bid - GPB;
        int k = tid;
        float s = 0.f, t = 0.f;
        if (k < DH) {
#pragma unroll
            for (int j = 0; j < DH; ++j) s += emb[j] * W1[j * DH + k];
            t = (s != 0.f) ? (-b1[k] / s) : INFINITY;
            ewl[k] = s; tl[k] = t; bl[k] = b1[k];
        }
        __syncthreads();
        if (k < DH) {
            int r = 0, ss = 0;
#pragma unroll
            for (int j = 0; j < DH; ++j) { r += (tl[j] <= t); ss += (tl[j] < t); }
            rl[k] = r; sl[k] = ss;
            if (beta == 0) tarr[k] = t;
        }
        __syncthreads();
        if (k < DH) {
            float p = 0.f, q = 0.f;
            for (int kk = 0; kk < DH; ++kk) {
                float e = ewl[kk];
                bool act;
                if (e > 0.f) act = (beta >= rl[kk]);
                else if (e < 0.f) act = (beta <= sl[kk]);
                else act = (bl[kk] > 0.f);
                if (act) {
                    float w = W2[kk * DH + k];
                    p += e * w;
                    q += bl[kk] * w;
                }
            }
            PQ[beta * DH + k] = make_float2(p, q);
        }
        return;
    }
    // ---- group part: local counting sort of chunk [c0,c1) ----
    int c0 = bid * chunk;
    int c1 = min(c0 + chunk, E);
    for (int t = tid; t < SCAN_N; t += 1024) lh[t] = 0;
    __syncthreads();
    for (int e = c0 + tid; e < c1; e += 1024)
        atomicAdd(&lh[dst[e] >> 6], 1);
    __syncthreads();
    for (int t = tid; t < SCAN_N; t += 1024) lb[t] = lh[t];
    __syncthreads();
    // inclusive scan of lb over SCAN_N (Hillis-Steele, 2 elems/thread)
    for (int ofs = 1; ofs < SCAN_N; ofs <<= 1) {
        int i1 = tid + 1024;
        int v0 = (tid >= ofs) ? lb[tid - ofs] : 0;
        int v1 = (i1 >= ofs) ? lb[i1 - ofs] : 0;
        __syncthreads();
        lb[tid] += v0; lb[i1] += v1;
        __syncthreads();
    }
    // exclusive base = incl - count; emit u16 index; keep base in lb
    size_t ib = (size_t)bid * (MAXNB + 1);
    for (int t = tid; t < NB; t += 1024) {
        int base = lb[t] - lh[t];
        idx[ib + t] = (unsigned short)base;
        lb[t] = base;
    }
    if (tid == 0) idx[ib + NB] = (unsigned short)(c1 - c0);
    __syncthreads();
    for (int t = tid; t < NB; t += 1024) lh[t] = 0;
    __syncthreads();
    // scatter into block-private dense region (writes stay within 50KB,
    // single-XCD, dense writeback; no cross-block line sharing)
    for (int e = c0 + tid; e < c1; e += 1024) {
        int s = src[e], dd = dst[e];
        int bk = dd >> 6;
        int o = lb[bk] + atomicAdd(&lh[bk], 1);
        rec[(size_t)bid * chunk + o] = (unsigned)s | ((unsigned)(dd & 63) << 26);
    }
}

// ---- pass A: OUTPUT-major merge of GPB runs per bucket. Each thread owns
// consecutive merged slots o and binary-searches the LDS run-prefix for its
// source run; rec2 stores coalesced. Also counts deg -> dinv. ----
__global__ __launch_bounds__(256) void k_passA(const unsigned short* __restrict__ idx,
        const unsigned* __restrict__ rec, unsigned* __restrict__ rec2,
        int* __restrict__ cnts, float* __restrict__ dinv, int N, int chunk) {
    __shared__ int rst[GPB];   // run start (global rec index)
    __shared__ int ps[GPB];    // inclusive prefix of run lengths
    __shared__ int cl[BW];
    int tid = threadIdx.x, bk = blockIdx.x;
    if (tid < BW) cl[tid] = 0;
    if (tid < GPB) {
        size_t ib = (size_t)tid * (MAXNB + 1);
        int s = idx[ib + bk];
        int e = idx[ib + bk + 1];
        rst[tid] = tid * chunk + s;
        ps[tid] = e - s;
    }
    __syncthreads();
    // inclusive scan of run lengths over GPB (128)
    for (int ofs = 1; ofs < GPB; ofs <<= 1) {
        int v = (tid < GPB && tid >= ofs) ? ps[tid - ofs] : 0;
        __syncthreads();
        if (tid < GPB) ps[tid] += v;
        __syncthreads();
    }
    int T = ps[GPB - 1];
    if (tid == 0) cnts[bk] = min(T, CAPE);
    size_t r2 = (size_t)bk * CAPE;
    for (int o = tid; o < T; o += 256) {
        // r = smallest index with ps[r] > o  (7-step binary search)
        int r = 0;
#pragma unroll
        for (int s = 64; s > 0; s >>= 1)
            if (r + s <= GPB && ps[r + s - 1] <= o) r += s;
        int base = (r > 0) ? ps[r - 1] : 0;
        unsigned v = rec[rst[r] + (o - base)];
        atomicAdd(&cl[v >> 26], 1);
        if (o < CAPE) rec2[r2 + o] = v;
    }
    __syncthreads();
    if (tid < BW) {
        int i = bk * BW + tid;
        if (i < N) dinv[i] = rsqrtf((float)cl[tid] + 1.0f);
    }
}

// ---- pass B: per-bucket S (uint4 rec2 loads, LDS atomics) -> summary4 ----
__global__ __launch_bounds__(256, 8) void k_passB(const int* __restrict__ cnts,
        const unsigned* __restrict__ rec2, const float* __restrict__ dinv,
        const float* __restrict__ tarr, float4* __restrict__ summary, int N) {
    __shared__ float Sl[BW];
    __shared__ float tl[DH];
    int tid = threadIdx.x;
    if (tid < BW) Sl[tid] = 0.f;
    if (tid < DH) tl[tid] = tarr[tid];
    __syncthreads();
    int b = blockIdx.x;
    int cnt = cnts[b];
    size_t r0 = (size_t)b * CAPE;
    const uint4* rq = (const uint4*)(rec2 + r0);  // r0*4 = b*5120, 16B aligned
    int nq = cnt >> 2;
    for (int q = tid; q < nq; q += blockDim.x) {
        uint4 r = rq[q];
        float d0 = dinv[r.x & SRCM];
        float d1 = dinv[r.y & SRCM];
        float d2 = dinv[r.z & SRCM];
        float d3 = dinv[r.w & SRCM];
        atomicAdd(&Sl[r.x >> 26], d0);
        atomicAdd(&Sl[r.y >> 26], d1);
        atomicAdd(&Sl[r.z >> 26], d2);
        atomicAdd(&Sl[r.w >> 26], d3);
    }
    int e = (nq << 2) + tid;
    if (e < cnt) {
        unsigned r = rec2[r0 + e];
        atomicAdd(&Sl[r >> 26], dinv[r & SRCM]);
    }
    __syncthreads();
    if (tid < BW) {
        int i = b * BW + tid;
        if (i < N) {
            float di = dinv[i];
            float c = di * (Sl[tid] + di);
            int bb = 0;
#pragma unroll
            for (int j = 0; j < DH; ++j) bb += (tl[j] < c);
            summary[i] = make_float4(di * c, di, __uint_as_float((unsigned)bb), 0.f);
        }
    }
}

// ---- pass C: AB accumulate (uint4 rec2, 2 LDS atomics/edge), dense u-loop
// with SOFTWARE-PIPELINED PQ prefetch (load PQ[u+1] while computing u),
// bin-64 column via LDS, self term + relu + SHARDED strip pooling. ----
__global__ __launch_bounds__(256, 4) void k_passC(const int* __restrict__ cnts,
        const unsigned* __restrict__ rec2, const float4* __restrict__ summary,
        const float2* __restrict__ PQ,
        const float* __restrict__ b2, const int* __restrict__ batch,
        float* __restrict__ psum_s, float* __restrict__ cnt_s, int N, int G) {
    __shared__ __align__(16) float AB[BW * NBIN * 2];  // 33,280 B
    int tid = threadIdx.x;  // 256
    // zero AB float4-wide (8320 floats = 2080 float4)
    float4* AB4 = (float4*)AB;
    for (int t = tid; t < (BW * NBIN * 2) / 4; t += blockDim.x)
        AB4[t] = make_float4(0.f, 0.f, 0.f, 0.f);
    __syncthreads();
    int b = blockIdx.x;
    int ecnt = cnts[b];
    size_t r0 = (size_t)b * CAPE;
    const uint4* rq = (const uint4*)(rec2 + r0);
    int nq = ecnt >> 2;
    for (int q = tid; q < nq; q += blockDim.x) {
        uint4 r = rq[q];
        float4 s0 = summary[r.x & SRCM];
        float4 s1 = summary[r.y & SRCM];
        float4 s2 = summary[r.z & SRCM];
        float4 s3 = summary[r.w & SRCM];
        float* p0 = &AB[(((r.x >> 26)) * NBIN + __float_as_uint(s0.z)) * 2];
        atomicAdd(p0, s0.x); atomicAdd(p0 + 1, s0.y);
        float* p1 = &AB[(((r.y >> 26)) * NBIN + __float_as_uint(s1.z)) * 2];
        atomicAdd(p1, s1.x); atomicAdd(p1 + 1, s1.y);
        float* p2 = &AB[(((r.z >> 26)) * NBIN + __float_as_uint(s2.z)) * 2];
        atomicAdd(p2, s2.x); atomicAdd(p2 + 1, s2.y);
        float* p3 = &AB[(((r.w >> 26)) * NBIN + __float_as_uint(s3.z)) * 2];
        atomicAdd(p3, s3.x); atomicAdd(p3 + 1, s3.y);
    }
    int e = (nq << 2) + tid;
    if (e < ecnt) {
        unsigned r = rec2[r0 + e];
        float4 sm = summary[r & SRCM];
        float* pp = &AB[((r >> 26) * NBIN + __float_as_uint(sm.z)) * 2];
        atomicAdd(pp, sm.x); atomicAdd(pp + 1, sm.y);
    }
    __syncthreads();
    int d = tid & 63;
    int w = tid >> 6;   // 0..3, wave w owns nodes [w*16, w*16+16)
    int n0b = w << 4;
    float2 abr[16];
#pragma unroll
    for (int j = 0; j < 16; ++j)
        abr[j] = *(const float2*)&AB[((n0b + j) * NBIN + d) * 2];
    float accv[16];
#pragma unroll
    for (int j = 0; j < 16; ++j) accv[j] = 0.f;
    // dense u-loop, PQ software-pipelined one iteration ahead
    const float2* PQd = PQ + d;
    float2 pqn = PQd[0];
    for (int u = 0; u < 64; ++u) {
        float2 pq = pqn;
        pqn = PQd[(u + 1) * DH];   // u+1 <= 64 < NBIN rows: always valid
#pragma unroll
        for (int j = 0; j < 16; ++j) {
            float ax = __int_as_float(__builtin_amdgcn_readlane(__float_as_int(abr[j].x), u));
            float ay = __int_as_float(__builtin_amdgcn_readlane(__float_as_int(abr[j].y), u));
            accv[j] += ax * pq.x + ay * pq.y;
        }
    }
    {   // bin 64 column via LDS broadcast (pqn holds PQ[64])
        float2 pq = pqn;
#pragma unroll
        for (int j = 0; j < 16; ++j) {
            float2 v = *(const float2*)&AB[((n0b + j) * NBIN + 64) * 2];
            accv[j] += v.x * pq.x + v.y * pq.y;
        }
    }
    // finish: self term + relu + sorted-batch strip pooling (sharded flush)
    float* psum = psum_s + (size_t)(b & (NSH - 1)) * G * DH;
    float* cnt  = cnt_s  + (size_t)(b & (NSH - 1)) * G;
    int n0 = b * BW;
    float bias = b2[d];
    float lsum = 0.f, lcnt = 0.f;
    int cb = -1;
    for (int j = 0; j < 16; ++j) {
        int i = n0 + n0b + j;
        if (i >= N) break;
        float4 sm = summary[i];
        int rb = (int)__float_as_uint(sm.z);
        float2 pq = PQd[rb * DH];
        float g = sm.x * pq.x + sm.y * pq.y;
        float v = fmaxf(sm.y * (accv[j] + g) + bias, 0.f);
        int bt = batch[i];
        if (bt != cb) {
            if (cb >= 0) {
                atomicAdd(&psum[cb * DH + d], lsum);
                if (d == 0) atomicAdd(&cnt[cb], lcnt);
            }
            cb = bt; lsum = 0.f; lcnt = 0.f;
        }
        lsum += v;
        if (d == 0) lcnt += 1.f;
    }
    if (cb >= 0) {
        atomicAdd(&psum[cb * DH + d], lsum);
        if (d == 0) atomicAdd(&cnt[cb], lcnt);
    }
}

// ---- out: one block per graph; reduce NSH shards, mean-pool, FC ----
__global__ __launch_bounds__(64) void k_out(const float* __restrict__ psum_s,
        const float* __restrict__ cnt_s, const float* __restrict__ fcW,
        const float* __restrict__ fcb, float* __restrict__ out, int G) {
    __shared__ float pooled[DH];
    int g = blockIdx.x, d = threadIdx.x;  // 64 threads
    float s = 0.f, cc = 0.f;
#pragma unroll
    for (int k = 0; k < NSH; ++k) {
        s += psum_s[(size_t)k * G * DH + g * DH + d];
        cc += cnt_s[(size_t)k * G + g];
    }
    pooled[d] = s / fmaxf(cc, 1.0f);
    __syncthreads();
    if (d < DOUT) {
        float o = 0.f;
#pragma unroll
        for (int kk = 0; kk < DH; ++kk) o += pooled[kk] * fcW[kk * DOUT + d];
        out[g * DOUT + d] = o + fcb[d];
    }
}

static inline size_t pad256(size_t n) { return (n + 255) & ~(size_t)255; }

extern "C" void kernel_launch(void* const* d_in, const int* in_sizes, int n_in,
                              void* d_out, int out_size, void* d_ws, size_t ws_size,
                              hipStream_t stream) {
    const int N = in_sizes[0];
    const int E = in_sizes[1] / 2;
    const int G = out_size / DOUT;
    const int NB = (N + BW - 1) / BW;
    const int chunk = (E + GPB - 1) / GPB;  // ~12500, fits u16

    const int* edge = (const int*)d_in[1];
    const int* src = edge;
    const int* dst = edge + E;
    const int* batch = (const int*)d_in[2];
    const float* emb = (const float*)d_in[3];
    const float* W1 = (const float*)d_in[4];
    const float* b1 = (const float*)d_in[5];
    const float* W2 = (const float*)d_in[6];
    const float* b2 = (const float*)d_in[7];
    const float* fcW = (const float*)d_in[8];
    const float* fcb = (const float*)d_in[9];
    float* out = (float*)d_out;

    // workspace. Zero region first: psum_s, cnt_s (~133 KB).
    char* ws = (char*)d_ws;
    size_t off = 0;
    float* psum_s = (float*)(ws + off); off += pad256((size_t)NSH * G * DH) * 4;
    float* cnt_s  = (float*)(ws + off); off += pad256((size_t)NSH * G) * 4;
    size_t zero_bytes = off;
    unsigned* rec  = (unsigned*)(ws + off); off += pad256((size_t)GPB * chunk) * 4;   // ~6.4 MB
    unsigned* rec2 = (unsigned*)(ws + off); off += pad256((size_t)MAXNB * CAPE) * 4;  // 10.5 MB
    unsigned short* idx = (unsigned short*)(ws + off);
    off += pad256((size_t)GPB * (MAXNB + 1)) * 2;                                     // ~525 KB
    int* cnts    = (int*)(ws + off);    off += pad256(MAXNB) * 4;
    float* dinv  = (float*)(ws + off);  off += pad256(N) * 4;
    float* tarr  = (float*)(ws + off);  off += pad256(DH) * 4;
    float2* PQ   = (float2*)(ws + off); off += pad256(NBIN * DH) * 8;
    float4* summary = (float4*)(ws + off); off += pad256(N) * 16;
    // total ~ 20 MB

    hipMemsetAsync(d_ws, 0, zero_bytes, stream);

    const int B = 256;
    k_group<<<GPB + NBIN, 1024, 0, stream>>>(src, dst, rec, idx, emb, W1, b1, W2,
                                             tarr, PQ, E, NB, chunk);
    k_passA<<<NB, B, 0, stream>>>(idx, rec, rec2, cnts, dinv, N, chunk);
    k_passB<<<NB, B, 0, stream>>>(cnts, rec2, dinv, tarr, summary, N);
    k_passC<<<NB, B, 0, stream>>>(cnts, rec2, summary, PQ, b2, batch,
                                  psum_s, cnt_s, N, G);
    k_out<<<G, 64, 0, stream>>>(psum_s, cnt_s, fcW, fcb, out, G);
}

// Round 7
// 165.766 us; speedup vs baseline: 1.3002x; 1.3002x over previous
//
#include <hip/hip_runtime.h>
#include <hip/hip_bf16.h>

// GCN fused pipeline for MI355X — block-local counting sort (NO global atomics,
// NO scattered global writes), binary-search output-major merge, LDS-local
// E-passes, 8-way sharded pooling atomics.
// vocab=1 => h1[i] = relu(embW1*c_i + b1) piecewise-linear in scalar c_i with
// <=65 ReLU patterns (bins). g[i] = a_i*P[bin_i] + b_i*Q[bin_i].
// agg_i[d] = sum_u A_i[u]*P[u][d] + B_i[u]*Q[u][d], (A,B) per-(node,bin) LDS
// sums (2 LDS atomics/edge).
// Lessons: R6 - no E-scale global atomics (64B line write-through each);
// R11 - no cooperative grid.sync (8 XCDs); R12 - contended global atomic
// flush is a 71us-class floor -> shard psum/cnt; R13 - raising k_group blocks
// WITH global cursor atomics quadruples atomic write-through; R14 - 512-thr
// passC regressed (VGPR cap); R15 - output-major merge passA; R16 - per-edge
// wave-serialized broadcast loop = ~235 cyc/edge latency chain (615us!) —
// keep edges parallel ACROSS LANES; R17 - k_group GPB 128->256 with 1024-thr
// blocks neutral: not block-count-bound; R18 - U IS SPARSE (~6 of 65 bins
// live: c_i range is narrow) — dense u-loop = 10x VALU work, passC 41->98us.
// KEEP the ballot/ulist sparse machinery.
// R19 (this round): k_group rebuilt as 256-thread (4-wave) blocks, GPB=512:
// barrier cost ~4x cheaper, hierarchical scan (8 buckets/thread in registers
// + 8-round HS over 256 wave-totals) replaces 11-round 2048-wide HS; 8
// resident blocks/CU hide histogram/scatter latency. passC/passB/k_out =
// known-good R0 form restored exactly.
// Inputs: 0 x[int32 N], 1 edge_index[int32 2*E] (src then dst), 2 batch[int32 N sorted],
// 3 emb[1*64], 4 W1[64*64], 5 b1[64], 6 W2[64*64], 7 b2[64], 8 fcW[64*32], 9 fcb[32].
// Output: [G=64, 32] fp32.

#define DH 64
#define DOUT 32
#define NBIN 65
#define BW 64          // bucket width (nodes per bucket)
#define MAXNB 2048     // max buckets (N <= 131072)
#define SCAN_N 2048    // scan width (>= NB, pow2)
#define SRCM 0x3FFFFFF // 26-bit src mask (N < 2^26)
#define CAPE 1280      // per-bucket compacted capacity (16B-aligned: 1280*4=5120)
#define GPB 512        // group blocks (pow2)
#define GT 256         // group block threads (4 waves)
#define NSH 8          // pooling shards

// ---- group: per-block LDS counting sort (4-wave blocks, hierarchical scan)
// -> block-private dense region + u16 run index. Extra NBIN blocks: PQ tables. ----
__global__ __launch_bounds__(256) void k_group(
        const int* __restrict__ src, const int* __restrict__ dst,
        unsigned* __restrict__ rec, unsigned short* __restrict__ idx,
        const float* __restrict__ emb, const float* __restrict__ W1,
        const float* __restrict__ b1, const float* __restrict__ W2,
        float* __restrict__ tarr, float2* __restrict__ PQ, int E, int NB, int chunk) {
    __shared__ int lh[SCAN_N];   // 8 KB: histogram, then scatter counters
    __shared__ int lb[SCAN_N];   // 8 KB: exclusive bases
    __shared__ int wt[GT];       // 1 KB: per-thread totals scan
    __shared__ float ewl[DH], tl[DH], bl[DH];
    __shared__ int rl[DH], sl[DH];
    int tid = threadIdx.x, bid = blockIdx.x;
    if (bid >= GPB) {
        // ---- tables part: beta = bid-GPB in 0..64, 64 working threads ----
        int beta = bid - GPB;
        int k = tid;
        float s = 0.f, t = 0.f;
        if (k < DH) {
#pragma unroll
            for (int j = 0; j < DH; ++j) s += emb[j] * W1[j * DH + k];
            t = (s != 0.f) ? (-b1[k] / s) : INFINITY;
            ewl[k] = s; tl[k] = t; bl[k] = b1[k];
        }
        __syncthreads();
        if (k < DH) {
            int r = 0, ss = 0;
#pragma unroll
            for (int j = 0; j < DH; ++j) { r += (tl[j] <= t); ss += (tl[j] < t); }
            rl[k] = r; sl[k] = ss;
            if (beta == 0) tarr[k] = t;
        }
        __syncthreads();
        if (k < DH) {
            float p = 0.f, q = 0.f;
            for (int kk = 0; kk < DH; ++kk) {
                float e = ewl[kk];
                bool act;
                if (e > 0.f) act = (beta >= rl[kk]);
                else if (e < 0.f) act = (beta <= sl[kk]);
                else act = (bl[kk] > 0.f);
                if (act) {
                    float w = W2[kk * DH + k];
                    p += e * w;
                    q += bl[kk] * w;
                }
            }
            PQ[beta * DH + k] = make_float2(p, q);
        }
        return;
    }
    // ---- group part: local counting sort of chunk [c0,c1) ----
    int c0 = bid * chunk;
    int c1 = min(c0 + chunk, E);
    for (int t = tid; t < SCAN_N; t += GT) lh[t] = 0;
    __syncthreads();
    for (int e = c0 + tid; e < c1; e += GT)
        atomicAdd(&lh[dst[e] >> 6], 1);
    __syncthreads();
    // hierarchical scan: 8 buckets/thread in registers, then HS over 256 totals
    int base8 = tid << 3;
    int l[8], pfx[8];
#pragma unroll
    for (int k = 0; k < 8; ++k) l[k] = lh[base8 + k];
    int tot = 0;
#pragma unroll
    for (int k = 0; k < 8; ++k) { pfx[k] = tot; tot += l[k]; }
    wt[tid] = tot;
    __syncthreads();
    for (int ofs = 1; ofs < GT; ofs <<= 1) {
        int v = (tid >= ofs) ? wt[tid - ofs] : 0;
        __syncthreads();
        wt[tid] += v;
        __syncthreads();
    }
    int excl = wt[tid] - tot;
    size_t ib = (size_t)bid * (MAXNB + 1);
#pragma unroll
    for (int k = 0; k < 8; ++k) {
        int v = excl + pfx[k];
        lb[base8 + k] = v;
        if (base8 + k < NB) idx[ib + base8 + k] = (unsigned short)v;
        lh[base8 + k] = 0;  // own range: safe (already read)
    }
    if (tid == 0) idx[ib + NB] = (unsigned short)(c1 - c0);
    __syncthreads();
    // scatter into block-private dense region (~12.5 KB, dense writeback)
    for (int e = c0 + tid; e < c1; e += GT) {
        int s = src[e], dd = dst[e];
        int bk = dd >> 6;
        int o = lb[bk] + atomicAdd(&lh[bk], 1);
        rec[(size_t)bid * chunk + o] = (unsigned)s | ((unsigned)(dd & 63) << 26);
    }
}

// ---- pass A: OUTPUT-major merge of GPB runs per bucket. Each thread owns
// consecutive merged slots o and binary-searches the LDS run-prefix for its
// source run; rec2 stores coalesced. Also counts deg -> dinv. ----
__global__ __launch_bounds__(256) void k_passA(const unsigned short* __restrict__ idx,
        const unsigned* __restrict__ rec, unsigned* __restrict__ rec2,
        int* __restrict__ cnts, float* __restrict__ dinv, int N, int chunk) {
    __shared__ int rst[GPB];   // run start (global rec index)
    __shared__ int ps[GPB];    // inclusive prefix of run lengths
    __shared__ int cl[BW];
    int tid = threadIdx.x, bk = blockIdx.x;
    if (tid < BW) cl[tid] = 0;
    for (int t = tid; t < GPB; t += 256) {
        size_t ib = (size_t)t * (MAXNB + 1);
        int s = idx[ib + bk];
        int e = idx[ib + bk + 1];
        rst[t] = t * chunk + s;
        ps[t] = e - s;
    }
    __syncthreads();
    // inclusive scan of run lengths over GPB=512 (2 elems/thread HS)
    for (int ofs = 1; ofs < GPB; ofs <<= 1) {
        int i0 = tid, i1 = tid + 256;
        int v0 = (i0 >= ofs) ? ps[i0 - ofs] : 0;
        int v1 = (i1 >= ofs) ? ps[i1 - ofs] : 0;
        __syncthreads();
        ps[i0] += v0; ps[i1] += v1;
        __syncthreads();
    }
    int T = ps[GPB - 1];
    if (tid == 0) cnts[bk] = min(T, CAPE);
    size_t r2 = (size_t)bk * CAPE;
    for (int o = tid; o < T; o += 256) {
        // r = smallest index with ps[r] > o  (9-step binary search, GPB=512)
        int r = 0;
#pragma unroll
        for (int s = 256; s > 0; s >>= 1)
            if (r + s <= GPB && ps[r + s - 1] <= o) r += s;
        int base = (r > 0) ? ps[r - 1] : 0;
        unsigned v = rec[rst[r] + (o - base)];
        atomicAdd(&cl[v >> 26], 1);
        if (o < CAPE) rec2[r2 + o] = v;
    }
    __syncthreads();
    if (tid < BW) {
        int i = bk * BW + tid;
        if (i < N) dinv[i] = rsqrtf((float)cl[tid] + 1.0f);
    }
}

// ---- pass B: per-bucket S (uint4 rec2 loads, LDS atomics) -> summary4, flags ----
__global__ __launch_bounds__(256, 8) void k_passB(const int* __restrict__ cnts,
        const unsigned* __restrict__ rec2, const float* __restrict__ dinv,
        const float* __restrict__ tarr, float4* __restrict__ summary,
        int* __restrict__ flags, int N) {
    __shared__ float Sl[BW];
    __shared__ float tl[DH];
    int tid = threadIdx.x;
    if (tid < BW) Sl[tid] = 0.f;
    if (tid < DH) tl[tid] = tarr[tid];
    __syncthreads();
    int b = blockIdx.x;
    int cnt = cnts[b];
    size_t r0 = (size_t)b * CAPE;
    const uint4* rq = (const uint4*)(rec2 + r0);  // r0*4 = b*5120, 16B aligned
    int nq = cnt >> 2;
    for (int q = tid; q < nq; q += blockDim.x) {
        uint4 r = rq[q];
        float d0 = dinv[r.x & SRCM];
        float d1 = dinv[r.y & SRCM];
        float d2 = dinv[r.z & SRCM];
        float d3 = dinv[r.w & SRCM];
        atomicAdd(&Sl[r.x >> 26], d0);
        atomicAdd(&Sl[r.y >> 26], d1);
        atomicAdd(&Sl[r.z >> 26], d2);
        atomicAdd(&Sl[r.w >> 26], d3);
    }
    int e = (nq << 2) + tid;
    if (e < cnt) {
        unsigned r = rec2[r0 + e];
        atomicAdd(&Sl[r >> 26], dinv[r & SRCM]);
    }
    __syncthreads();
    if (tid < BW) {
        int i = b * BW + tid;
        if (i < N) {
            float di = dinv[i];
            float c = di * (Sl[tid] + di);
            int bb = 0;
#pragma unroll
            for (int j = 0; j < DH; ++j) bb += (tl[j] < c);
            summary[i] = make_float4(di * c, di, __uint_as_float((unsigned)bb), 0.f);
            flags[bb] = 1;  // benign race: same value
        }
    }
}

// ---- pass C: AB accumulate (uint4 rec2, 2 LDS atomics/edge), compact ulist +
// readlane U-dot (U ~ 6 sparse bins), self term + relu + SHARDED strip
// pooling. (known-good round-0 256-thread version) ----
__global__ __launch_bounds__(256, 4) void k_passC(const int* __restrict__ cnts,
        const unsigned* __restrict__ rec2, const float4* __restrict__ summary,
        const float2* __restrict__ PQ, const int* __restrict__ flags,
        const float* __restrict__ b2, const int* __restrict__ batch,
        float* __restrict__ psum_s, float* __restrict__ cnt_s, int N, int G) {
    __shared__ __align__(16) float AB[BW * NBIN * 2];  // 33,280 B
    __shared__ unsigned char ulist[NBIN + 3];
    __shared__ int UcntS;
    int tid = threadIdx.x;  // 256
    // used-bin list via ballot
    if (tid < 64) {
        int act = (flags[tid] != 0);
        unsigned long long m = __ballot(act);
        int pos = __popcll(m & ((1ull << tid) - 1ull));
        if (act) ulist[pos] = (unsigned char)tid;
        if (tid == 0) {
            int total = __popcll(m);
            if (flags[64]) ulist[total++] = 64;
            UcntS = total;
        }
    }
    // zero AB float4-wide (8320 floats = 2080 float4)
    float4* AB4 = (float4*)AB;
    for (int t = tid; t < (BW * NBIN * 2) / 4; t += blockDim.x)
        AB4[t] = make_float4(0.f, 0.f, 0.f, 0.f);
    __syncthreads();
    int b = blockIdx.x;
    int ecnt = cnts[b];
    size_t r0 = (size_t)b * CAPE;
    const uint4* rq = (const uint4*)(rec2 + r0);
    int nq = ecnt >> 2;
    for (int q = tid; q < nq; q += blockDim.x) {
        uint4 r = rq[q];
        float4 s0 = summary[r.x & SRCM];
        float4 s1 = summary[r.y & SRCM];
        float4 s2 = summary[r.z & SRCM];
        float4 s3 = summary[r.w & SRCM];
        float* p0 = &AB[(((r.x >> 26)) * NBIN + __float_as_uint(s0.z)) * 2];
        atomicAdd(p0, s0.x); atomicAdd(p0 + 1, s0.y);
        float* p1 = &AB[(((r.y >> 26)) * NBIN + __float_as_uint(s1.z)) * 2];
        atomicAdd(p1, s1.x); atomicAdd(p1 + 1, s1.y);
        float* p2 = &AB[(((r.z >> 26)) * NBIN + __float_as_uint(s2.z)) * 2];
        atomicAdd(p2, s2.x); atomicAdd(p2 + 1, s2.y);
        float* p3 = &AB[(((r.w >> 26)) * NBIN + __float_as_uint(s3.z)) * 2];
        atomicAdd(p3, s3.x); atomicAdd(p3 + 1, s3.y);
    }
    int e = (nq << 2) + tid;
    if (e < ecnt) {
        unsigned r = rec2[r0 + e];
        float4 sm = summary[r & SRCM];
        float* pp = &AB[((r >> 26) * NBIN + __float_as_uint(sm.z)) * 2];
        atomicAdd(pp, sm.x); atomicAdd(pp + 1, sm.y);
    }
    __syncthreads();
    int U = UcntS;
    int d = tid & 63;
    int w = tid >> 6;   // 0..3, wave w owns nodes [w*16, w*16+16)
    int n0b = w << 4;
    float2 abr[16];
#pragma unroll
    for (int j = 0; j < 16; ++j)
        abr[j] = *(const float2*)&AB[((n0b + j) * NBIN + d) * 2];
    float accv[16];
#pragma unroll
    for (int j = 0; j < 16; ++j) accv[j] = 0.f;
    for (int uu = 0; uu < U; ++uu) {
        int u = ulist[uu];  // wave-uniform
        float2 pq = PQ[u * DH + d];
        if (u < 64) {
#pragma unroll
            for (int j = 0; j < 16; ++j) {
                float ax = __int_as_float(__builtin_amdgcn_readlane(__float_as_int(abr[j].x), u));
                float ay = __int_as_float(__builtin_amdgcn_readlane(__float_as_int(abr[j].y), u));
                accv[j] += ax * pq.x + ay * pq.y;
            }
        } else {
#pragma unroll
            for (int j = 0; j < 16; ++j) {
                float2 v = *(const float2*)&AB[((n0b + j) * NBIN + 64) * 2];
                accv[j] += v.x * pq.x + v.y * pq.y;
            }
        }
    }
    // finish: self term + relu + sorted-batch strip pooling (sharded flush)
    float* psum = psum_s + (size_t)(b & (NSH - 1)) * G * DH;
    float* cnt  = cnt_s  + (size_t)(b & (NSH - 1)) * G;
    int n0 = b * BW;
    float bias = b2[d];
    float lsum = 0.f, lcnt = 0.f;
    int cb = -1;
    for (int j = 0; j < 16; ++j) {
        int i = n0 + n0b + j;
        if (i >= N) break;
        float4 sm = summary[i];
        int rb = (int)__float_as_uint(sm.z);
        float2 pq = PQ[rb * DH + d];
        float g = sm.x * pq.x + sm.y * pq.y;
        float v = fmaxf(sm.y * (accv[j] + g) + bias, 0.f);
        int bt = batch[i];
        if (bt != cb) {
            if (cb >= 0) {
                atomicAdd(&psum[cb * DH + d], lsum);
                if (d == 0) atomicAdd(&cnt[cb], lcnt);
            }
            cb = bt; lsum = 0.f; lcnt = 0.f;
        }
        lsum += v;
        if (d == 0) lcnt += 1.f;
    }
    if (cb >= 0) {
        atomicAdd(&psum[cb * DH + d], lsum);
        if (d == 0) atomicAdd(&cnt[cb], lcnt);
    }
}

// ---- out: one block per graph; reduce NSH shards, mean-pool, FC ----
__global__ __launch_bounds__(64) void k_out(const float* __restrict__ psum_s,
        const float* __restrict__ cnt_s, const float* __restrict__ fcW,
        const float* __restrict__ fcb, float* __restrict__ out, int G) {
    __shared__ float pooled[DH];
    int g = blockIdx.x, d = threadIdx.x;  // 64 threads
    float s = 0.f, cc = 0.f;
#pragma unroll
    for (int k = 0; k < NSH; ++k) {
        s += psum_s[(size_t)k * G * DH + g * DH + d];
        cc += cnt_s[(size_t)k * G + g];
    }
    pooled[d] = s / fmaxf(cc, 1.0f);
    __syncthreads();
    if (d < DOUT) {
        float o = 0.f;
#pragma unroll
        for (int kk = 0; kk < DH; ++kk) o += pooled[kk] * fcW[kk * DOUT + d];
        out[g * DOUT + d] = o + fcb[d];
    }
}

static inline size_t pad256(size_t n) { return (n + 255) & ~(size_t)255; }

extern "C" void kernel_launch(void* const* d_in, const int* in_sizes, int n_in,
                              void* d_out, int out_size, void* d_ws, size_t ws_size,
                              hipStream_t stream) {
    const int N = in_sizes[0];
    const int E = in_sizes[1] / 2;
    const int G = out_size / DOUT;
    const int NB = (N + BW - 1) / BW;
    int chunk = (E + GPB - 1) / GPB;
    chunk = (chunk + 3) & ~3;  // 16B-align block regions; ~3128 fits u16

    const int* edge = (const int*)d_in[1];
    const int* src = edge;
    const int* dst = edge + E;
    const int* batch = (const int*)d_in[2];
    const float* emb = (const float*)d_in[3];
    const float* W1 = (const float*)d_in[4];
    const float* b1 = (const float*)d_in[5];
    const float* W2 = (const float*)d_in[6];
    const float* b2 = (const float*)d_in[7];
    const float* fcW = (const float*)d_in[8];
    const float* fcb = (const float*)d_in[9];
    float* out = (float*)d_out;

    // workspace. Zero region first: psum_s, cnt_s, flags (~135 KB).
    char* ws = (char*)d_ws;
    size_t off = 0;
    float* psum_s = (float*)(ws + off); off += pad256((size_t)NSH * G * DH) * 4;
    float* cnt_s  = (float*)(ws + off); off += pad256((size_t)NSH * G) * 4;
    int* flags  = (int*)(ws + off);    off += pad256(NBIN) * 4;
    size_t zero_bytes = off;
    unsigned* rec  = (unsigned*)(ws + off); off += pad256((size_t)GPB * chunk) * 4;   // ~6.4 MB
    unsigned* rec2 = (unsigned*)(ws + off); off += pad256((size_t)MAXNB * CAPE) * 4;  // 10.5 MB
    unsigned short* idx = (unsigned short*)(ws + off);
    off += pad256((size_t)GPB * (MAXNB + 1)) * 2;                                     // ~2.1 MB
    int* cnts    = (int*)(ws + off);    off += pad256(MAXNB) * 4;
    float* dinv  = (float*)(ws + off);  off += pad256(N) * 4;
    float* tarr  = (float*)(ws + off);  off += pad256(DH) * 4;
    float2* PQ   = (float2*)(ws + off); off += pad256(NBIN * DH) * 8;
    float4* summary = (float4*)(ws + off); off += pad256(N) * 16;
    // total ~ 22 MB

    hipMemsetAsync(d_ws, 0, zero_bytes, stream);

    const int B = 256;
    k_group<<<GPB + NBIN, GT, 0, stream>>>(src, dst, rec, idx, emb, W1, b1, W2,
                                           tarr, PQ, E, NB, chunk);
    k_passA<<<NB, B, 0, stream>>>(idx, rec, rec2, cnts, dinv, N, chunk);
    k_passB<<<NB, B, 0, stream>>>(cnts, rec2, dinv, tarr, summary, flags, N);
    k_passC<<<NB, B, 0, stream>>>(cnts, rec2, summary, PQ, flags, b2, batch,
                                  psum_s, cnt_s, N, G);
    k_out<<<G, 64, 0, stream>>>(psum_s, cnt_s, fcW, fcb, out, G);
}

// Round 8
// 156.935 us; speedup vs baseline: 1.3733x; 1.0563x over previous
//
#include <hip/hip_runtime.h>
#include <hip/hip_bf16.h>

// GCN fused pipeline for MI355X — fixed-capacity dst-bucket grouping,
// LDS-local E-passes, 8-way sharded pooling atomics, COMPACT-BIN passC.
// vocab=1 => h1[i] = relu(embW1*c_i + b1) piecewise-linear in scalar c_i with
// <=65 ReLU patterns (bins). g[i] = a_i*P[bin_i] + b_i*Q[bin_i].
// agg_i[d] = sum_u A_i[u]*P[u][d] + B_i[u]*Q[u][d], (A,B) per-(node,bin) LDS
// sums (2 LDS atomics/edge).
// Lessons: R6 - no E-scale global atomics (64B line write-through each);
// R11 - no cooperative grid.sync (8 XCDs); R12 - contended global-atomic
// flush floor -> shard psum/cnt; R13 - more blocks with global cursor
// atomics = 4x atomic write-through; R14 - 512-thr passC spilled (VGPR cap);
// R15/R17/R19 - three front-end restructures all ~neutral: k_group's ~40us
// is a scattered-WRITE-path wall (25.9MB @ 622GB/s, cross-XCD partial-line
// sharing), not latency/barriers/blocks; R16 - never wave-serialize per-edge
// work (235cy/edge chain = 615us); R18 - U IS SPARSE (~6 of 65 bins live) —
// keep ballot/ulist. ALSO: the harness's ~41.5us 256MB workspace poison-fill
// is INSIDE dur_us; controllable budget ~115us.
// R20 (this round): passC AB indexed by COMPACT bin — [64][16+pad][2] = 8.7KB
// LDS (was 33.3KB dense over 65 bins) -> occupancy cap 4->6+ blocks/CU to
// hide the per-edge summary gathers. bmap[bin] u8 LDS read per edge; U>16
// falls back to multi-group re-streaming (correct for any input). Front end
// = R0 verbatim (best measured: 156.7).
// Inputs: 0 x[int32 N], 1 edge_index[int32 2*E] (src then dst), 2 batch[int32 N sorted],
// 3 emb[1*64], 4 W1[64*64], 5 b1[64], 6 W2[64*64], 7 b2[64], 8 fcW[64*32], 9 fcb[32].
// Output: [G=64, 32] fp32.

#define DH 64
#define DOUT 32
#define NBIN 65
#define BW 64          // bucket width (nodes per bucket)
#define MAXNB 2048     // max buckets (N <= 131072)
#define SRCM 0x3FFFFFF // 26-bit src mask (N < 2^26)
#define CAPE 1280      // per-bucket record capacity (16B-aligned: 1280*4=5120)
#define GPB 128        // group blocks
#define NSH 8          // pooling shards
#define UMAX 16        // compact-bin slots per pass
#define NST 17         // padded node stride in float2 (bank = 2(dd+cu)%32)

// ---- group edges by dst bucket (fixed capacity) + PQ tables in extra blocks ----
__global__ __launch_bounds__(1024) void k_group(
        const int* __restrict__ src, const int* __restrict__ dst,
        int* __restrict__ cursor, unsigned* __restrict__ rec,
        const float* __restrict__ emb, const float* __restrict__ W1,
        const float* __restrict__ b1, const float* __restrict__ W2,
        float* __restrict__ tarr, float2* __restrict__ PQ, int E, int NB, int chunk) {
    __shared__ int lh[MAXNB];
    __shared__ int lb[MAXNB];
    __shared__ float ewl[DH], tl[DH], bl[DH];
    __shared__ int rl[DH], sl[DH];
    int tid = threadIdx.x, bid = blockIdx.x;
    if (bid >= GPB) {
        // ---- tables part: beta = bid-GPB in 0..64, 64 working threads ----
        int beta = bid - GPB;
        int k = tid;
        float s = 0.f, t = 0.f;
        if (k < DH) {
#pragma unroll
            for (int j = 0; j < DH; ++j) s += emb[j] * W1[j * DH + k];
            t = (s != 0.f) ? (-b1[k] / s) : INFINITY;
            ewl[k] = s; tl[k] = t; bl[k] = b1[k];
        }
        __syncthreads();
        if (k < DH) {
            int r = 0, ss = 0;
#pragma unroll
            for (int j = 0; j < DH; ++j) { r += (tl[j] <= t); ss += (tl[j] < t); }
            rl[k] = r; sl[k] = ss;
            if (beta == 0) tarr[k] = t;
        }
        __syncthreads();
        if (k < DH) {
            float p = 0.f, q = 0.f;
            for (int kk = 0; kk < DH; ++kk) {
                float e = ewl[kk];
                bool act;
                if (e > 0.f) act = (beta >= rl[kk]);
                else if (e < 0.f) act = (beta <= sl[kk]);
                else act = (bl[kk] > 0.f);
                if (act) {
                    float w = W2[kk * DH + k];
                    p += e * w;
                    q += bl[kk] * w;
                }
            }
            PQ[beta * DH + k] = make_float2(p, q);
        }
        return;
    }
    // ---- group part ----
    int c0 = bid * chunk;
    int c1 = min(c0 + chunk, E);
    for (int t = tid; t < NB; t += blockDim.x) lh[t] = 0;
    __syncthreads();
    for (int e = c0 + tid; e < c1; e += blockDim.x)
        atomicAdd(&lh[dst[e] >> 6], 1);
    __syncthreads();
    for (int t = tid; t < NB; t += blockDim.x) {
        int h = lh[t];
        lb[t] = h ? atomicAdd(&cursor[t], h) : 0;
    }
    __syncthreads();
    for (int t = tid; t < NB; t += blockDim.x) lh[t] = 0;
    __syncthreads();
    for (int e = c0 + tid; e < c1; e += blockDim.x) {
        int s = src[e], dd = dst[e];
        int bk = dd >> 6;
        int ofs = lb[bk] + atomicAdd(&lh[bk], 1);
        if (ofs < CAPE)  // 8-sigma safety clamp
            rec[bk * CAPE + ofs] = (unsigned)s | ((unsigned)(dd & 63) << 26);
    }
}

// ---- pass A: per-bucket deg count (LDS, coalesced rec stream) -> dinv ----
__global__ __launch_bounds__(256) void k_passA(const int* __restrict__ cursor,
        const unsigned* __restrict__ rec, float* __restrict__ dinv, int N) {
    __shared__ int cl[BW];
    int tid = threadIdx.x;
    if (tid < BW) cl[tid] = 0;
    __syncthreads();
    int b = blockIdx.x;
    int cnt = min(cursor[b], CAPE);
    int r0 = b * CAPE;
    for (int e = tid; e < cnt; e += blockDim.x)
        atomicAdd(&cl[rec[r0 + e] >> 26], 1);
    __syncthreads();
    if (tid < BW) {
        int i = b * BW + tid;
        if (i < N) dinv[i] = rsqrtf((float)cl[tid] + 1.0f);
    }
}

// ---- pass B: per-bucket S (uint4 rec loads, LDS atomics) -> summary4, flags ----
__global__ __launch_bounds__(256, 8) void k_passB(const int* __restrict__ cursor,
        const unsigned* __restrict__ rec, const float* __restrict__ dinv,
        const float* __restrict__ tarr, float4* __restrict__ summary,
        int* __restrict__ flags, int N) {
    __shared__ float Sl[BW];
    __shared__ float tl[DH];
    int tid = threadIdx.x;
    if (tid < BW) Sl[tid] = 0.f;
    if (tid < DH) tl[tid] = tarr[tid];
    __syncthreads();
    int b = blockIdx.x;
    int cnt = min(cursor[b], CAPE);
    int r0 = b * CAPE;
    const uint4* rq = (const uint4*)(rec + r0);  // r0*4 = b*5120, 16B aligned
    int nq = cnt >> 2;
    for (int q = tid; q < nq; q += blockDim.x) {
        uint4 r = rq[q];
        float d0 = dinv[r.x & SRCM];
        float d1 = dinv[r.y & SRCM];
        float d2 = dinv[r.z & SRCM];
        float d3 = dinv[r.w & SRCM];
        atomicAdd(&Sl[r.x >> 26], d0);
        atomicAdd(&Sl[r.y >> 26], d1);
        atomicAdd(&Sl[r.z >> 26], d2);
        atomicAdd(&Sl[r.w >> 26], d3);
    }
    int e = (nq << 2) + tid;
    if (e < cnt) {
        unsigned r = rec[r0 + e];
        atomicAdd(&Sl[r >> 26], dinv[r & SRCM]);
    }
    __syncthreads();
    if (tid < BW) {
        int i = b * BW + tid;
        if (i < N) {
            float di = dinv[i];
            float c = di * (Sl[tid] + di);
            int bb = 0;
#pragma unroll
            for (int j = 0; j < DH; ++j) bb += (tl[j] < c);
            summary[i] = make_float4(di * c, di, __uint_as_float((unsigned)bb), 0.f);
            flags[bb] = 1;  // benign race: same value
        }
    }
}

// ---- pass C: COMPACT-BIN AB accumulate. AB[64][NST][2] = 8.7KB (was 33.3KB
// dense) -> occupancy 4 -> 6+ blocks/CU. bmap[bin] -> compact slot per edge;
// U>16 handled by multi-group re-streaming (predicate free when U<=16).
// Readlane U-dot over compact lanes; self term + relu + SHARDED strip pool. ----
__global__ __launch_bounds__(256, 6) void k_passC(const int* __restrict__ cursor,
        const unsigned* __restrict__ rec, const float4* __restrict__ summary,
        const float2* __restrict__ PQ, const int* __restrict__ flags,
        const float* __restrict__ b2, const int* __restrict__ batch,
        float* __restrict__ psum_s, float* __restrict__ cnt_s, int N, int G) {
    __shared__ __align__(16) float AB[BW * NST * 2];  // 8,704 B
    __shared__ unsigned char ulist[NBIN + 3];
    __shared__ unsigned char bmap[NBIN + 3];
    __shared__ int UcntS;
    int tid = threadIdx.x;  // 256
    // used-bin list + bin->compact map via ballot
    if (tid < 64) {
        int act = (flags[tid] != 0);
        unsigned long long m = __ballot(act);
        int pos = __popcll(m & ((1ull << tid) - 1ull));
        if (act) { ulist[pos] = (unsigned char)tid; bmap[tid] = (unsigned char)pos; }
        if (tid == 0) {
            int total = __popcll(m);
            if (flags[64]) { ulist[total] = 64; bmap[64] = (unsigned char)total; total++; }
            UcntS = total;
        }
    }
    __syncthreads();
    int U = UcntS;
    int b = blockIdx.x;
    int ecnt = min(cursor[b], CAPE);
    int r0 = b * CAPE;
    const uint4* rq = (const uint4*)(rec + r0);
    int nq = ecnt >> 2;
    int d = tid & 63;
    int w = tid >> 6;   // 0..3, wave w owns nodes [w*16, w*16+16)
    int n0b = w << 4;
    float accv[16];
#pragma unroll
    for (int j = 0; j < 16; ++j) accv[j] = 0.f;
    for (int g0 = 0; g0 < U; g0 += UMAX) {
        int gend = min(U, g0 + UMAX);
        // zero AB (2176 floats = 544 float4)
        float4* AB4 = (float4*)AB;
        for (int t = tid; t < (BW * NST * 2) / 4; t += 256)
            AB4[t] = make_float4(0.f, 0.f, 0.f, 0.f);
        __syncthreads();
        for (int q = tid; q < nq; q += 256) {
            uint4 r = rq[q];
            float4 s0 = summary[r.x & SRCM];
            float4 s1 = summary[r.y & SRCM];
            float4 s2 = summary[r.z & SRCM];
            float4 s3 = summary[r.w & SRCM];
            int cb0 = (int)bmap[__float_as_uint(s0.z)] - g0;
            int cb1 = (int)bmap[__float_as_uint(s1.z)] - g0;
            int cb2 = (int)bmap[__float_as_uint(s2.z)] - g0;
            int cb3 = (int)bmap[__float_as_uint(s3.z)] - g0;
            if ((unsigned)cb0 < UMAX) {
                float* p = &AB[((r.x >> 26) * NST + cb0) * 2];
                atomicAdd(p, s0.x); atomicAdd(p + 1, s0.y);
            }
            if ((unsigned)cb1 < UMAX) {
                float* p = &AB[((r.y >> 26) * NST + cb1) * 2];
                atomicAdd(p, s1.x); atomicAdd(p + 1, s1.y);
            }
            if ((unsigned)cb2 < UMAX) {
                float* p = &AB[((r.z >> 26) * NST + cb2) * 2];
                atomicAdd(p, s2.x); atomicAdd(p + 1, s2.y);
            }
            if ((unsigned)cb3 < UMAX) {
                float* p = &AB[((r.w >> 26) * NST + cb3) * 2];
                atomicAdd(p, s3.x); atomicAdd(p + 1, s3.y);
            }
        }
        int e = (nq << 2) + tid;
        if (e < ecnt) {
            unsigned r = rec[r0 + e];
            float4 sm = summary[r & SRCM];
            int cb = (int)bmap[__float_as_uint(sm.z)] - g0;
            if ((unsigned)cb < UMAX) {
                float* p = &AB[((r >> 26) * NST + cb) * 2];
                atomicAdd(p, sm.x); atomicAdd(p + 1, sm.y);
            }
        }
        __syncthreads();
        // lane d<16 holds compact slot (d&15) of each node; readlane broadcasts
        float2 abr[16];
#pragma unroll
        for (int j = 0; j < 16; ++j)
            abr[j] = *(const float2*)&AB[((n0b + j) * NST + (d & 15)) * 2];
        for (int uu = g0; uu < gend; ++uu) {
            int lane = uu - g0;          // wave-uniform, 0..15
            int u = ulist[uu];
            float2 pq = PQ[u * DH + d];
#pragma unroll
            for (int j = 0; j < 16; ++j) {
                float ax = __int_as_float(__builtin_amdgcn_readlane(__float_as_int(abr[j].x), lane));
                float ay = __int_as_float(__builtin_amdgcn_readlane(__float_as_int(abr[j].y), lane));
                accv[j] += ax * pq.x + ay * pq.y;
            }
        }
        if (g0 + UMAX < U) __syncthreads();  // uniform branch; protect re-zero
    }
    // finish: self term + relu + sorted-batch strip pooling (sharded flush)
    float* psum = psum_s + (size_t)(b & (NSH - 1)) * G * DH;
    float* cnt  = cnt_s  + (size_t)(b & (NSH - 1)) * G;
    int n0 = b * BW;
    float bias = b2[d];
    float lsum = 0.f, lcnt = 0.f;
    int cb = -1;
    for (int j = 0; j < 16; ++j) {
        int i = n0 + n0b + j;
        if (i >= N) break;
        float4 sm = summary[i];
        int rb = (int)__float_as_uint(sm.z);
        float2 pq = PQ[rb * DH + d];
        float g = sm.x * pq.x + sm.y * pq.y;
        float v = fmaxf(sm.y * (accv[j] + g) + bias, 0.f);
        int bt = batch[i];
        if (bt != cb) {
            if (cb >= 0) {
                atomicAdd(&psum[cb * DH + d], lsum);
                if (d == 0) atomicAdd(&cnt[cb], lcnt);
            }
            cb = bt; lsum = 0.f; lcnt = 0.f;
        }
        lsum += v;
        if (d == 0) lcnt += 1.f;
    }
    if (cb >= 0) {
        atomicAdd(&psum[cb * DH + d], lsum);
        if (d == 0) atomicAdd(&cnt[cb], lcnt);
    }
}

// ---- out: one block per graph; reduce NSH shards, mean-pool, FC ----
__global__ __launch_bounds__(64) void k_out(const float* __restrict__ psum_s,
        const float* __restrict__ cnt_s, const float* __restrict__ fcW,
        const float* __restrict__ fcb, float* __restrict__ out, int G) {
    __shared__ float pooled[DH];
    int g = blockIdx.x, d = threadIdx.x;  // 64 threads
    float s = 0.f, cc = 0.f;
#pragma unroll
    for (int k = 0; k < NSH; ++k) {
        s += psum_s[(size_t)k * G * DH + g * DH + d];
        cc += cnt_s[(size_t)k * G + g];
    }
    pooled[d] = s / fmaxf(cc, 1.0f);
    __syncthreads();
    if (d < DOUT) {
        float o = 0.f;
#pragma unroll
        for (int kk = 0; kk < DH; ++kk) o += pooled[kk] * fcW[kk * DOUT + d];
        out[g * DOUT + d] = o + fcb[d];
    }
}

static inline size_t pad256(size_t n) { return (n + 255) & ~(size_t)255; }

extern "C" void kernel_launch(void* const* d_in, const int* in_sizes, int n_in,
                              void* d_out, int out_size, void* d_ws, size_t ws_size,
                              hipStream_t stream) {
    const int N = in_sizes[0];
    const int E = in_sizes[1] / 2;
    const int G = out_size / DOUT;
    const int NB = (N + BW - 1) / BW;

    const int* edge = (const int*)d_in[1];
    const int* src = edge;
    const int* dst = edge + E;
    const int* batch = (const int*)d_in[2];
    const float* emb = (const float*)d_in[3];
    const float* W1 = (const float*)d_in[4];
    const float* b1 = (const float*)d_in[5];
    const float* W2 = (const float*)d_in[6];
    const float* b2 = (const float*)d_in[7];
    const float* fcW = (const float*)d_in[8];
    const float* fcb = (const float*)d_in[9];
    float* out = (float*)d_out;

    // workspace. Zero region first: psum_s, cnt_s, flags, cursor (~160 KB).
    char* ws = (char*)d_ws;
    size_t off = 0;
    float* psum_s = (float*)(ws + off); off += pad256((size_t)NSH * G * DH) * 4;
    float* cnt_s  = (float*)(ws + off); off += pad256((size_t)NSH * G) * 4;
    int* flags  = (int*)(ws + off);    off += pad256(NBIN) * 4;
    int* cursor = (int*)(ws + off);    off += pad256(MAXNB) * 4;
    size_t zero_bytes = off;
    unsigned* rec = (unsigned*)(ws + off); off += pad256((size_t)MAXNB * CAPE) * 4;  // 10.5 MB
    float* dinv  = (float*)(ws + off);  off += pad256(N) * 4;
    float* tarr  = (float*)(ws + off);  off += pad256(DH) * 4;
    float2* PQ   = (float2*)(ws + off); off += pad256(NBIN * DH) * 8;
    float4* summary = (float4*)(ws + off); off += pad256(N) * 16;
    // total ~ 13 MB

    hipMemsetAsync(d_ws, 0, zero_bytes, stream);

    const int B = 256;
    int chunk = (E + GPB - 1) / GPB;
    k_group<<<GPB + NBIN, 1024, 0, stream>>>(src, dst, cursor, rec, emb, W1, b1, W2,
                                             tarr, PQ, E, NB, chunk);
    k_passA<<<NB, B, 0, stream>>>(cursor, rec, dinv, N);
    k_passB<<<NB, B, 0, stream>>>(cursor, rec, dinv, tarr, summary, flags, N);
    k_passC<<<NB, B, 0, stream>>>(cursor, rec, summary, PQ, flags, b2, batch,
                                  psum_s, cnt_s, N, G);
    k_out<<<G, 64, 0, stream>>>(psum_s, cnt_s, fcW, fcb, out, G);
}